// Round 5
// baseline (150.842 us; speedup 1.0000x reference)
//
#include <hip/hip_runtime.h>
#include <math.h>

#define KNN 5
#define BLOCK 256
#define TILE_T 2048
#define WAVES_PER_BLOCK (BLOCK / 64)
#define SRCW 8
#define SRC_PER_BLOCK (WAVES_PER_BLOCK * SRCW)  // 32
#define NSPLIT 2

// ---- grid (cell list) parameters ----
#define G 28
#define NC (G * G * G)          // 21952 cells
#define GRANGE 6.0f             // grid covers [-6,6]^3; cell indices clamped
#define H (2.0f * GRANGE / G)   // 0.428571
#define INVH ((float)G / (2.0f * GRANGE))
#define SCHUNK 22               // cells per thread in scan (1024*22 >= NC)
#define LPS 16                  // lanes per source in query kernel

// ---------------- raw single-instruction min/max ----------------
__device__ __forceinline__ float vmin(float a, float b) {
    float r;
    asm("v_min_f32 %0, %1, %2" : "=v"(r) : "v"(a), "v"(b));
    return r;
}
__device__ __forceinline__ float vmax(float a, float b) {
    float r;
    asm("v_max_f32 %0, %1, %2" : "=v"(r) : "v"(a), "v"(b));
    return r;
}

// Online sorted top-5 insert: min(Kb,max(Ka,v)) == med3(Ka,Kb,v) for Ka<=Kb.
#define INS5(K0, K1, K2, K3, K4, V)                                       \
    do {                                                                  \
        float _v = (V);                                                   \
        K4 = __builtin_amdgcn_fmed3f(K3, K4, _v);                         \
        K3 = __builtin_amdgcn_fmed3f(K2, K3, _v);                         \
        K2 = __builtin_amdgcn_fmed3f(K1, K2, _v);                         \
        K1 = __builtin_amdgcn_fmed3f(K0, K1, _v);                         \
        K0 = vmin(K0, _v);                                                \
    } while (0)

// lowest-5 of two sorted-5 lists (result in a0..a4)
#define MERGE55(a0, a1, a2, a3, a4, b0, b1, b2, b3, b4)                   \
    do {                                                                  \
        float r0 = vmin(a0, b0);                                          \
        float r1 = vmin(vmin(a1, b1), vmax(a0, b0));                      \
        float r2 = vmin(vmin(a2, b2), vmin(vmax(a0, b1), vmax(a1, b0)));  \
        float r3 = vmin(vmin(a3, b3),                                     \
                        vmin(vmax(a0, b2), vmin(vmax(a1, b1), vmax(a2, b0)))); \
        float r4 = vmin(vmin(a4, b4),                                     \
                        vmin(vmin(vmax(a0, b3), vmax(a1, b2)),            \
                             vmin(vmax(a2, b1), vmax(a3, b0))));          \
        a0 = r0; a1 = r1; a2 = r2; a3 = r3; a4 = r4;                      \
    } while (0)

// ---------------- small utility kernels ----------------

__global__ void finalize_kernel(const float* acc, float* out) {
    out[0] = acc[0] / (acc[1] * (float)KNN);
}

__global__ void init_acc_kernel(float* acc) {
    acc[0] = 0.0f;
    acc[1] = 0.0f;
}

// ================= grid path =================

__global__ void grid_init_kernel(int* cnt_t, int* cnt_s, float* acc, int nc) {
    int i = blockIdx.x * blockDim.x + threadIdx.x;
    if (i == 0) { acc[0] = 0.0f; acc[1] = 0.0f; }
    for (; i < nc; i += gridDim.x * blockDim.x) {
        cnt_t[i] = 0;
        cnt_s[i] = 0;
    }
}

__device__ __forceinline__ int cell_of(float x, float y, float z) {
    int cx = (int)floorf((x + GRANGE) * INVH);
    int cy = (int)floorf((y + GRANGE) * INVH);
    int cz = (int)floorf((z + GRANGE) * INVH);
    cx = min(max(cx, 0), G - 1);
    cy = min(max(cy, 0), G - 1);
    cz = min(max(cz, 0), G - 1);
    return (cz * G + cy) * G + cx;
}

__global__ void bin_count_kernel(const float* __restrict__ src,
                                 const float* __restrict__ tgt,
                                 int ms, int nt,
                                 int* __restrict__ cnt_s,
                                 int* __restrict__ cnt_t) {
    int i = blockIdx.x * blockDim.x + threadIdx.x;
    int n = ms + nt;
    for (; i < n; i += gridDim.x * blockDim.x) {
        bool isT = (i >= ms);
        const float* p = isT ? (tgt + 3 * (size_t)(i - ms)) : (src + 3 * (size_t)i);
        float x = p[0], y = p[1], z = p[2];
        if (isT && x == 0.0f && y == 0.0f && z == 0.0f) continue;  // invalid target
        atomicAdd((isT ? cnt_t : cnt_s) + cell_of(x, y, z), 1);
    }
}

// one block per array (gridDim.x == 2): exclusive scan of NC counts.
// Writes off[0..NC] (off[NC]=total) and resets cnt[i] to off[i] (cursor).
__global__ __launch_bounds__(1024) void scan_kernel(int* cnt_t, int* off_t,
                                                    int* cnt_s, int* off_s) {
    __shared__ int psum[1024];
    int* c = blockIdx.x ? cnt_s : cnt_t;
    int* o = blockIdx.x ? off_s : off_t;
    const int tid = threadIdx.x;
    const int lo = tid * SCHUNK;

    int buf[SCHUNK];
    int s = 0;
#pragma unroll
    for (int j = 0; j < SCHUNK; ++j) {
        int i = lo + j;
        int v = (i < NC) ? c[i] : 0;
        buf[j] = v;
        s += v;
    }
    psum[tid] = s;
    __syncthreads();
    for (int d = 1; d < 1024; d <<= 1) {
        int v = (tid >= d) ? psum[tid - d] : 0;
        __syncthreads();
        psum[tid] += v;
        __syncthreads();
    }
    int run = tid ? psum[tid - 1] : 0;
#pragma unroll
    for (int j = 0; j < SCHUNK; ++j) {
        int i = lo + j;
        if (i < NC) {
            o[i] = run;
            c[i] = run;  // cursor for scatter
            run += buf[j];
        }
    }
    if (tid == 1023) o[NC] = psum[1023];
}

__global__ void scatter_kernel(const float* __restrict__ src,
                               const float* __restrict__ tgt,
                               int ms, int nt,
                               int* __restrict__ cur_s, int* __restrict__ cur_t,
                               float4* __restrict__ pts_s,
                               float4* __restrict__ pts_t) {
    int i = blockIdx.x * blockDim.x + threadIdx.x;
    int n = ms + nt;
    for (; i < n; i += gridDim.x * blockDim.x) {
        bool isT = (i >= ms);
        const float* p = isT ? (tgt + 3 * (size_t)(i - ms)) : (src + 3 * (size_t)i);
        float x = p[0], y = p[1], z = p[2];
        if (isT && x == 0.0f && y == 0.0f && z == 0.0f) continue;
        int cell = cell_of(x, y, z);
        int slot = atomicAdd((isT ? cur_t : cur_s) + cell, 1);
        float w = fmaf(x, x, fmaf(y, y, z * z));
        (isT ? pts_t : pts_s)[slot] = make_float4(x, y, z, w);
    }
}

// Query: 16 lanes per (cell-sorted) source; expanding Chebyshev shells with
// exact merged-K4 stop bound (unscanned cells are >= r*H away after shell r).
__global__ __launch_bounds__(BLOCK) void knn_grid_kernel(
        const float4* __restrict__ pts_s, const float4* __restrict__ pts_t,
        const int* __restrict__ off_t, float* __restrict__ acc, int ms) {
    __shared__ float red_s[BLOCK / LPS];
    __shared__ float red_c[BLOCK / LPS];

    const int tid = threadIdx.x;
    const int g = tid / LPS;        // group (source) within block
    const int m = tid % LPS;        // lane within group
    const int sidx = blockIdx.x * (BLOCK / LPS) + g;
    const bool live = (sidx < ms);

    float4 sp = pts_s[live ? sidx : 0];
    const float sx = sp.x, sy = sp.y, sz = sp.z, s2 = sp.w;
    const float nx = -2.0f * sx, ny = -2.0f * sy, nz = -2.0f * sz;

    int cx = (int)floorf((sx + GRANGE) * INVH);
    int cy = (int)floorf((sy + GRANGE) * INVH);
    int cz = (int)floorf((sz + GRANGE) * INVH);
    cx = min(max(cx, 0), G - 1);
    cy = min(max(cy, 0), G - 1);
    cz = min(max(cz, 0), G - 1);

    float q0 = 1e30f, q1 = 1e30f, q2 = 1e30f, q3 = 1e30f, q4 = 1e30f;

    auto scan_row = [&](int cyy, int czz, int xlo, int xhi) {
        if ((unsigned)cyy >= G || (unsigned)czz >= G) return;
        xlo = max(xlo, 0);
        xhi = min(xhi, G - 1);
        if (xlo > xhi) return;
        int base = (czz * G + cyy) * G;
        int st = off_t[base + xlo];
        int en = off_t[base + xhi + 1];
        for (int i = st + m; i < en; i += LPS) {
            float4 p = pts_t[i];
            float q = fmaf(nx, p.x, fmaf(ny, p.y, fmaf(nz, p.z, p.w)));
            INS5(q0, q1, q2, q3, q4, q);
        }
    };

    // merged (exact) top-5 snapshot, updated at each shell check
    float m0 = 1e30f, m1 = 1e30f, m2 = 1e30f, m3 = 1e30f, m4 = 1e30f;

    scan_row(cy, cz, cx, cx);  // r = 0: own cell
    for (int r = 1; r < G; ++r) {
        for (int dz = -r; dz <= r; ++dz) {
            int czz = cz + dz;
            int adz = dz < 0 ? -dz : dz;
            for (int dy = -r; dy <= r; ++dy) {
                int cyy = cy + dy;
                int ady = dy < 0 ? -dy : dy;
                if (adz == r || ady == r) {
                    scan_row(cyy, czz, cx - r, cx + r);
                } else {
                    scan_row(cyy, czz, cx - r, cx - r);
                    scan_row(cyy, czz, cx + r, cx + r);
                }
            }
        }
        // exact merged K4 via non-destructive butterfly within the 16-lane group
        m0 = q0; m1 = q1; m2 = q2; m3 = q3; m4 = q4;
#pragma unroll
        for (int o = 1; o < LPS; o <<= 1) {
            float b0 = __shfl_xor(m0, o);
            float b1 = __shfl_xor(m1, o);
            float b2 = __shfl_xor(m2, o);
            float b3 = __shfl_xor(m3, o);
            float b4 = __shfl_xor(m4, o);
            MERGE55(m0, m1, m2, m3, m4, b0, b1, b2, b3, b4);
        }
        float rh = (float)r * H;
        // stop if global 5th-smallest d^2 (= m4 + s2) <= (r*H)^2
        if (m4 <= fmaf(rh, rh, -s2)) break;
    }

    float ssum = 0.0f, scnt = 0.0f;
    if (live && m == 0) {
        bool valid = (sx != 0.0f) || (sy != 0.0f) || (sz != 0.0f);
        if (valid) {
            ssum = sqrtf(fmaxf(m0 + s2, 1e-12f)) + sqrtf(fmaxf(m1 + s2, 1e-12f)) +
                   sqrtf(fmaxf(m2 + s2, 1e-12f)) + sqrtf(fmaxf(m3 + s2, 1e-12f)) +
                   sqrtf(fmaxf(m4 + s2, 1e-12f));
            scnt = 1.0f;
        }
    }
    if (m == 0) {
        red_s[g] = ssum;
        red_c[g] = scnt;
    }
    __syncthreads();
    if (tid == 0) {
        float s = 0.0f, c = 0.0f;
#pragma unroll
        for (int i = 0; i < BLOCK / LPS; ++i) { s += red_s[i]; c += red_c[i]; }
        atomicAdd(&acc[0], s);
        atomicAdd(&acc[1], c);
    }
}

// ================= fallback: round-4 split path =================

__global__ __launch_bounds__(BLOCK, 4) void knn_split_kernel(
        const float* __restrict__ src, const float* __restrict__ tgt,
        float* __restrict__ partials, int ms, int nt, int nth, int spad) {
    __shared__ __align__(16) float xs[TILE_T];
    __shared__ __align__(16) float ys[TILE_T];
    __shared__ __align__(16) float zs[TILE_T];
    __shared__ __align__(16) float w2[TILE_T];

    const int tid = threadIdx.x;
    const int wv = tid >> 6;
    const int lane = tid & 63;
    const int sbase = (blockIdx.x * WAVES_PER_BLOCK + wv) * SRCW;
    const int half = blockIdx.y;
    const int hbase = half * nth;
    const int hend = min(nt, hbase + nth);

    float nx[SRCW], ny[SRCW], nz[SRCW];
#pragma unroll
    for (int s = 0; s < SRCW; ++s) {
        int sp = sbase + s;
        float x = 0.0f, y = 0.0f, z = 0.0f;
        if (sp < ms) {
            x = src[3 * sp + 0];
            y = src[3 * sp + 1];
            z = src[3 * sp + 2];
        }
        nx[s] = -2.0f * x;
        ny[s] = -2.0f * y;
        nz[s] = -2.0f * z;
    }

    float q0[SRCW], q1[SRCW], q2[SRCW], q3[SRCW], q4[SRCW];
#pragma unroll
    for (int s = 0; s < SRCW; ++s) {
        q0[s] = 1e30f; q1[s] = 1e30f; q2[s] = 1e30f; q3[s] = 1e30f; q4[s] = 1e30f;
    }

    for (int t0 = hbase; t0 < hend; t0 += TILE_T) {
        if (t0 + TILE_T <= hend) {
#pragma unroll
            for (int cc = 0; cc < TILE_T / 4; cc += BLOCK) {
                int c = cc + tid;
                const float4* t4 = reinterpret_cast<const float4*>(tgt + (size_t)t0 * 3);
                float4 f0 = t4[3 * c + 0];
                float4 f1 = t4[3 * c + 1];
                float4 f2 = t4[3 * c + 2];
                float px[4] = {f0.x, f0.w, f1.z, f2.y};
                float py[4] = {f0.y, f1.x, f1.w, f2.z};
                float pz[4] = {f0.z, f1.y, f2.x, f2.w};
                float pw[4];
#pragma unroll
                for (int j = 0; j < 4; ++j) {
                    bool v = (px[j] != 0.0f) || (py[j] != 0.0f) || (pz[j] != 0.0f);
                    if (!v) { px[j] = 1e10f; py[j] = 0.0f; pz[j] = 0.0f; }
                    pw[j] = fmaf(px[j], px[j], fmaf(py[j], py[j], pz[j] * pz[j]));
                }
                int t = 4 * c;
                *reinterpret_cast<float4*>(&xs[t]) = make_float4(px[0], px[1], px[2], px[3]);
                *reinterpret_cast<float4*>(&ys[t]) = make_float4(py[0], py[1], py[2], py[3]);
                *reinterpret_cast<float4*>(&zs[t]) = make_float4(pz[0], pz[1], pz[2], pz[3]);
                *reinterpret_cast<float4*>(&w2[t]) = make_float4(pw[0], pw[1], pw[2], pw[3]);
            }
        } else {
            int cnt = hend - t0;
            for (int t = tid; t < TILE_T; t += BLOCK) {
                float x = 1e10f, y = 0.0f, z = 0.0f;
                if (t < cnt) {
                    x = tgt[3 * (size_t)(t0 + t) + 0];
                    y = tgt[3 * (size_t)(t0 + t) + 1];
                    z = tgt[3 * (size_t)(t0 + t) + 2];
                    if (x == 0.0f && y == 0.0f && z == 0.0f) { x = 1e10f; y = 0.0f; z = 0.0f; }
                }
                xs[t] = x; ys[t] = y; zs[t] = z;
                w2[t] = fmaf(x, x, fmaf(y, y, z * z));
            }
        }
        __syncthreads();

#pragma unroll 2
        for (int i = 0; i < TILE_T / 256; ++i) {
            int t = (i << 8) + (lane << 2);
            float4 x4 = *reinterpret_cast<const float4*>(&xs[t]);
            float4 y4 = *reinterpret_cast<const float4*>(&ys[t]);
            float4 z4 = *reinterpret_cast<const float4*>(&zs[t]);
            float4 w4 = *reinterpret_cast<const float4*>(&w2[t]);
#pragma unroll
            for (int s = 0; s < SRCW; ++s) {
                float qa = fmaf(nx[s], x4.x, fmaf(ny[s], y4.x, fmaf(nz[s], z4.x, w4.x)));
                float qb = fmaf(nx[s], x4.y, fmaf(ny[s], y4.y, fmaf(nz[s], z4.y, w4.y)));
                float qc = fmaf(nx[s], x4.z, fmaf(ny[s], y4.z, fmaf(nz[s], z4.z, w4.z)));
                float qd = fmaf(nx[s], x4.w, fmaf(ny[s], y4.w, fmaf(nz[s], z4.w, w4.w)));
                INS5(q0[s], q1[s], q2[s], q3[s], q4[s], qa);
                INS5(q0[s], q1[s], q2[s], q3[s], q4[s], qb);
                INS5(q0[s], q1[s], q2[s], q3[s], q4[s], qc);
                INS5(q0[s], q1[s], q2[s], q3[s], q4[s], qd);
            }
        }
        __syncthreads();
    }

#pragma unroll
    for (int off = 32; off >= 1; off >>= 1) {
#pragma unroll
        for (int s = 0; s < SRCW; ++s) {
            float b0 = __shfl_xor(q0[s], off);
            float b1 = __shfl_xor(q1[s], off);
            float b2 = __shfl_xor(q2[s], off);
            float b3 = __shfl_xor(q3[s], off);
            float b4 = __shfl_xor(q4[s], off);
            MERGE55(q0[s], q1[s], q2[s], q3[s], q4[s], b0, b1, b2, b3, b4);
        }
    }

    if (lane == 0) {
        float* base = partials + ((size_t)half * spad + sbase) * 8;
#pragma unroll
        for (int s = 0; s < SRCW; ++s) {
            if (sbase + s < ms) {
                *reinterpret_cast<float4*>(base + 8 * s) =
                    make_float4(q0[s], q1[s], q2[s], q3[s]);
                *reinterpret_cast<float4*>(base + 8 * s + 4) =
                    make_float4(q4[s], 0.0f, 0.0f, 0.0f);
            }
        }
    }
}

__global__ __launch_bounds__(BLOCK) void merge_kernel(
        const float* __restrict__ src, const float* __restrict__ partials,
        float* __restrict__ acc, int ms, int spad) {
    __shared__ float red_s[WAVES_PER_BLOCK];
    __shared__ float red_c[WAVES_PER_BLOCK];

    const int tid = threadIdx.x;
    const int sp = blockIdx.x * BLOCK + tid;

    float ssum = 0.0f, scnt = 0.0f;
    if (sp < ms) {
        const float* r0p = partials + (size_t)sp * 8;
        const float* r1p = partials + ((size_t)spad + sp) * 8;
        float4 lo0 = *reinterpret_cast<const float4*>(r0p);
        float a4 = r0p[4];
        float4 lo1 = *reinterpret_cast<const float4*>(r1p);
        float b4 = r1p[4];
        float a0 = lo0.x, a1 = lo0.y, a2 = lo0.z, a3 = lo0.w;
        MERGE55(a0, a1, a2, a3, a4, lo1.x, lo1.y, lo1.z, lo1.w, b4);

        float x = src[3 * sp + 0];
        float y = src[3 * sp + 1];
        float z = src[3 * sp + 2];
        bool valid = (x != 0.0f) || (y != 0.0f) || (z != 0.0f);
        float s2 = fmaf(x, x, fmaf(y, y, z * z));
        if (valid) {
            ssum = sqrtf(fmaxf(a0 + s2, 1e-12f)) + sqrtf(fmaxf(a1 + s2, 1e-12f)) +
                   sqrtf(fmaxf(a2 + s2, 1e-12f)) + sqrtf(fmaxf(a3 + s2, 1e-12f)) +
                   sqrtf(fmaxf(a4 + s2, 1e-12f));
            scnt = 1.0f;
        }
    }
#pragma unroll
    for (int off = 32; off >= 1; off >>= 1) {
        ssum += __shfl_down(ssum, off);
        scnt += __shfl_down(scnt, off);
    }
    if ((tid & 63) == 0) {
        red_s[tid >> 6] = ssum;
        red_c[tid >> 6] = scnt;
    }
    __syncthreads();
    if (tid == 0) {
        float s = 0.0f, c = 0.0f;
#pragma unroll
        for (int i = 0; i < WAVES_PER_BLOCK; ++i) { s += red_s[i]; c += red_c[i]; }
        atomicAdd(&acc[0], s);
        atomicAdd(&acc[1], c);
    }
}

// ---------------- launch ----------------

extern "C" void kernel_launch(void* const* d_in, const int* in_sizes, int n_in,
                              void* d_out, int out_size, void* d_ws, size_t ws_size,
                              hipStream_t stream) {
    const float* src = (const float*)d_in[0];
    const float* tgt = (const float*)d_in[1];
    const int ms = in_sizes[0] / 3;
    const int nt = in_sizes[1] / 3;

    // ---- grid-path workspace layout ----
    char* p = (char*)d_ws;
    auto take = [&p](size_t bytes) {
        char* r = p;
        p += (bytes + 15) & ~(size_t)15;
        return r;
    };
    float* acc   = (float*)take(2 * sizeof(float));
    int* off_t   = (int*)take((NC + 1) * sizeof(int));
    int* cnt_t   = (int*)take(NC * sizeof(int));
    int* off_s   = (int*)take((NC + 1) * sizeof(int));
    int* cnt_s   = (int*)take(NC * sizeof(int));
    float4* pts_t = (float4*)take((size_t)nt * sizeof(float4));
    float4* pts_s = (float4*)take((size_t)ms * sizeof(float4));
    const size_t need_grid = (size_t)(p - (char*)d_ws);

    if (ws_size >= need_grid) {
        const int n = ms + nt;
        grid_init_kernel<<<128, 256, 0, stream>>>(cnt_t, cnt_s, acc, NC);
        bin_count_kernel<<<(n + 255) / 256, 256, 0, stream>>>(src, tgt, ms, nt, cnt_s, cnt_t);
        scan_kernel<<<2, 1024, 0, stream>>>(cnt_t, off_t, cnt_s, off_s);
        scatter_kernel<<<(n + 255) / 256, 256, 0, stream>>>(src, tgt, ms, nt,
                                                            cnt_s, cnt_t, pts_s, pts_t);
        const int qblocks = (ms + (BLOCK / LPS) - 1) / (BLOCK / LPS);
        knn_grid_kernel<<<qblocks, BLOCK, 0, stream>>>(pts_s, pts_t, off_t, acc, ms);
        finalize_kernel<<<1, 1, 0, stream>>>(acc, (float*)d_out);
        return;
    }

    // ---- fallback: round-4 split path ----
    float* acc2 = (float*)d_ws;
    init_acc_kernel<<<1, 1, 0, stream>>>(acc2);
    const int ngroups = (ms + SRC_PER_BLOCK - 1) / SRC_PER_BLOCK;
    const int spad = ngroups * SRC_PER_BLOCK;
    int nth = (nt + NSPLIT - 1) / NSPLIT;
    nth = (nth + TILE_T - 1) / TILE_T * TILE_T;
    float* partials = (float*)((char*)d_ws + 16);
    dim3 grid(ngroups, NSPLIT);
    knn_split_kernel<<<grid, BLOCK, 0, stream>>>(src, tgt, partials, ms, nt, nth, spad);
    merge_kernel<<<(ms + BLOCK - 1) / BLOCK, BLOCK, 0, stream>>>(src, partials, acc2, ms, spad);
    finalize_kernel<<<1, 1, 0, stream>>>(acc2, (float*)d_out);
}

// Round 6
// 129.966 us; speedup vs baseline: 1.1606x; 1.1606x over previous
//
#include <hip/hip_runtime.h>
#include <math.h>

#define KNN 5
#define BLOCK 256

// ---- cell grid ----
#define G 28
#define NC (G * G * G)        // 21952
#define NCPAD 24576           // 24*1024 (padded for the scan kernel)
#define GRANGE 6.0f
#define H (2.0f * GRANGE / (float)G)
#define INVH ((float)G / (2.0f * GRANGE))
#define CAP 3072              // LDS candidate capacity (48 KB)

// ---- fallback (round-4 split path) params ----
#define TILE_T 2048
#define WAVES_PER_BLOCK (BLOCK / 64)
#define SRCW 8
#define SRC_PER_BLOCK (WAVES_PER_BLOCK * SRCW)
#define NSPLIT 2

// ---------------- raw single-instruction min/max ----------------
__device__ __forceinline__ float vmin(float a, float b) {
    float r;
    asm("v_min_f32 %0, %1, %2" : "=v"(r) : "v"(a), "v"(b));
    return r;
}
__device__ __forceinline__ float vmax(float a, float b) {
    float r;
    asm("v_max_f32 %0, %1, %2" : "=v"(r) : "v"(a), "v"(b));
    return r;
}

// sorted top-5 insert: min(Kb,max(Ka,v)) == med3(Ka,Kb,v) for Ka<=Kb
#define INS5(K0, K1, K2, K3, K4, V)                                       \
    do {                                                                  \
        float _v = (V);                                                   \
        K4 = __builtin_amdgcn_fmed3f(K3, K4, _v);                         \
        K3 = __builtin_amdgcn_fmed3f(K2, K3, _v);                         \
        K2 = __builtin_amdgcn_fmed3f(K1, K2, _v);                         \
        K1 = __builtin_amdgcn_fmed3f(K0, K1, _v);                         \
        K0 = vmin(K0, _v);                                                \
    } while (0)

// lowest-5 of two sorted-5 lists (result in a0..a4)
#define MERGE55(a0, a1, a2, a3, a4, b0, b1, b2, b3, b4)                   \
    do {                                                                  \
        float r0 = vmin(a0, b0);                                          \
        float r1 = vmin(vmin(a1, b1), vmax(a0, b0));                      \
        float r2 = vmin(vmin(a2, b2), vmin(vmax(a0, b1), vmax(a1, b0)));  \
        float r3 = vmin(vmin(a3, b3),                                     \
                        vmin(vmax(a0, b2), vmin(vmax(a1, b1), vmax(a2, b0)))); \
        float r4 = vmin(vmin(a4, b4),                                     \
                        vmin(vmin(vmax(a0, b3), vmax(a1, b2)),            \
                             vmin(vmax(a2, b1), vmax(a3, b0))));          \
        a0 = r0; a1 = r1; a2 = r2; a3 = r3; a4 = r4;                      \
    } while (0)

// ---------------- tiny kernels ----------------
__global__ void finalize_kernel(const float* acc, float* out) {
    out[0] = acc[0] / (acc[1] * (float)KNN);
}
__global__ void init_acc_kernel(float* acc) { acc[0] = 0.0f; acc[1] = 0.0f; }

// ================= grid pipeline =================

__device__ __forceinline__ int cell_of(float x, float y, float z) {
    int cx = (int)floorf((x + GRANGE) * INVH);
    int cy = (int)floorf((y + GRANGE) * INVH);
    int cz = (int)floorf((z + GRANGE) * INVH);
    cx = min(max(cx, 0), G - 1);
    cy = min(max(cy, 0), G - 1);
    cz = min(max(cz, 0), G - 1);
    return (cz * G + cy) * G + cx;
}

__global__ void bin_count_kernel(const float* __restrict__ src,
                                 const float* __restrict__ tgt,
                                 int ms, int nt,
                                 int* __restrict__ cnt_s,
                                 int* __restrict__ cnt_t) {
    int i = blockIdx.x * blockDim.x + threadIdx.x;
    int n = ms + nt;
    for (; i < n; i += gridDim.x * blockDim.x) {
        bool isT = (i >= ms);
        const float* p = isT ? (tgt + 3 * (size_t)(i - ms)) : (src + 3 * (size_t)i);
        float x = p[0], y = p[1], z = p[2];
        if (isT && x == 0.0f && y == 0.0f && z == 0.0f) continue;
        atomicAdd((isT ? cnt_t : cnt_s) + cell_of(x, y, z), 1);
    }
}

// exclusive scan of NCPAD padded counts (pads are zero from the memset).
// gridDim.x == 2: block 0 -> targets, block 1 -> sources.
__global__ __launch_bounds__(1024) void scan_kernel(int* ct, int* ot, int* cs, int* os) {
    __shared__ int psum[1024];
    int* c = blockIdx.x ? cs : ct;
    int* o = blockIdx.x ? os : ot;
    const int t = threadIdx.x;
    int4 v[6];
    const int4* c4 = reinterpret_cast<const int4*>(c) + t * 6;
#pragma unroll
    for (int j = 0; j < 6; ++j) v[j] = c4[j];
    int s = 0;
#pragma unroll
    for (int j = 0; j < 6; ++j) s += v[j].x + v[j].y + v[j].z + v[j].w;
    psum[t] = s;
    __syncthreads();
    for (int d = 1; d < 1024; d <<= 1) {
        int x = (t >= d) ? psum[t - d] : 0;
        __syncthreads();
        psum[t] += x;
        __syncthreads();
    }
    int run = t ? psum[t - 1] : 0;
    int4* o4 = reinterpret_cast<int4*>(o) + t * 6;
    int4* cc4 = reinterpret_cast<int4*>(c) + t * 6;
#pragma unroll
    for (int j = 0; j < 6; ++j) {
        int4 w;
        w.x = run; run += v[j].x;
        w.y = run; run += v[j].y;
        w.z = run; run += v[j].z;
        w.w = run; run += v[j].w;
        o4[j] = w;
        cc4[j] = w;  // cursor for scatter
    }
    if (t == 1023) o[NCPAD] = run;
}

__global__ void scatter_kernel(const float* __restrict__ src,
                               const float* __restrict__ tgt,
                               int ms, int nt,
                               int* __restrict__ cur_s, int* __restrict__ cur_t,
                               float4* __restrict__ pts_s,
                               float4* __restrict__ pts_t) {
    int i = blockIdx.x * blockDim.x + threadIdx.x;
    int n = ms + nt;
    for (; i < n; i += gridDim.x * blockDim.x) {
        bool isT = (i >= ms);
        const float* p = isT ? (tgt + 3 * (size_t)(i - ms)) : (src + 3 * (size_t)i);
        float x = p[0], y = p[1], z = p[2];
        if (isT && x == 0.0f && y == 0.0f && z == 0.0f) continue;
        int cell = cell_of(x, y, z);
        int slot = atomicAdd((isT ? cur_t : cur_s) + cell, 1);
        float w = fmaf(x, x, fmaf(y, y, z * z));
        (isT ? pts_t : pts_s)[slot] = make_float4(x, y, z, w);
    }
}

// ---- kernel A: block = source cell, ring<=1, LDS-staged, 8 lanes/source ----
__global__ __launch_bounds__(BLOCK) void knnA_kernel(
        const float4* __restrict__ pts_s, const float4* __restrict__ pts_t,
        const int* __restrict__ off_s, const int* __restrict__ off_t,
        float* __restrict__ acc, int* __restrict__ tail,
        int* __restrict__ tailcnt) {
    __shared__ __align__(16) float4 cand[CAP];
    __shared__ float redS[4], redC[4];

    const int cell = blockIdx.x;
    const int s0 = off_s[cell];
    const int S = off_s[cell + 1] - s0;
    if (S == 0) return;

    const int cx = cell % G;
    const int cy = (cell / G) % G;
    const int cz = cell / (G * G);
    const int xlo = max(cx - 1, 0), xhi = min(cx + 1, G - 1);

    const int DY[9] = {0, -1, 1, 0, 0, -1, -1, 1, 1};
    const int DZ[9] = {0, 0, 0, -1, 1, -1, 1, -1, 1};

    int rst[9], rlen[9], rof[9];
    float ry0[9], ry1[9], rz0[9], rz1[9];
    int C = 0;
#pragma unroll
    for (int r = 0; r < 9; ++r) {
        int yy = cy + DY[r], zz = cz + DZ[r];
        bool ok = (yy >= 0) && (yy < G) && (zz >= 0) && (zz < G);
        int base = (zz * G + yy) * G;
        int st = ok ? off_t[base + xlo] : 0;
        int en = ok ? off_t[base + xhi + 1] : st;
        rst[r] = st;
        rlen[r] = en - st;
        rof[r] = C;
        C += en - st;
        ry0[r] = -GRANGE + yy * H; ry1[r] = ry0[r] + H;
        rz0[r] = -GRANGE + zz * H; rz1[r] = rz0[r] + H;
    }

    const int tid = threadIdx.x;
    const bool useLds = (C <= CAP);
    if (useLds) {
#pragma unroll
        for (int r = 0; r < 9; ++r)
            for (int i = tid; i < rlen[r]; i += BLOCK)
                cand[rof[r] + i] = pts_t[rst[r] + i];
        __syncthreads();
    }

    const int slot = tid >> 3, l8 = tid & 7;
    float tsum = 0.0f, tcnt = 0.0f;

    for (int p0 = 0; p0 < S; p0 += 32) {
        const int si = p0 + slot;
        const bool live = (si < S);
        float4 sp = pts_s[s0 + (live ? si : 0)];
        const float s2 = sp.w;
        const float nx = -2.0f * sp.x, ny = -2.0f * sp.y, nz = -2.0f * sp.z;
        float q0 = 1e20f, q1 = 1e20f, q2 = 1e20f, q3 = 1e20f, q4 = 1e20f;

#pragma unroll
        for (int r = 0; r < 9; ++r) {
            if (rlen[r] == 0) continue;  // block-uniform
            float dy = fmaxf(0.0f, fmaxf(ry0[r] - sp.y, sp.y - ry1[r]));
            float dz = fmaxf(0.0f, fmaxf(rz0[r] - sp.z, sp.z - rz1[r]));
            float rb = fmaf(dy, dy, dz * dz);
            bool go = live && (q4 + s2 > rb);  // prune row if d5^2 <= bound
            if (go) {
                if (useLds) {
                    const float4* cp = cand + rof[r];
                    for (int i = l8; i < rlen[r]; i += 8) {
                        float4 t = cp[i];
                        float q = fmaf(nx, t.x, fmaf(ny, t.y, fmaf(nz, t.z, t.w)));
                        INS5(q0, q1, q2, q3, q4, q);
                    }
                } else {
                    const float4* cp = pts_t + rst[r];
                    for (int i = l8; i < rlen[r]; i += 8) {
                        float4 t = cp[i];
                        float q = fmaf(nx, t.x, fmaf(ny, t.y, fmaf(nz, t.z, t.w)));
                        INS5(q0, q1, q2, q3, q4, q);
                    }
                }
            }
        }

        // merge the 8 lanes of this source (butterfly, all lanes get result)
#pragma unroll
        for (int off = 4; off >= 1; off >>= 1) {
            float b0 = __shfl_xor(q0, off);
            float b1 = __shfl_xor(q1, off);
            float b2 = __shfl_xor(q2, off);
            float b3 = __shfl_xor(q3, off);
            float b4 = __shfl_xor(q4, off);
            MERGE55(q0, q1, q2, q3, q4, b0, b1, b2, b3, b4);
        }

        if (l8 == 0 && live) {
            bool valid = (sp.x != 0.0f) || (sp.y != 0.0f) || (sp.z != 0.0f);
            if (valid) {
                bool inbox = fabsf(sp.x) <= GRANGE && fabsf(sp.y) <= GRANGE &&
                             fabsf(sp.z) <= GRANGE;
                // done iff exact: unscanned points are >= H away
                if (inbox && (q4 + s2 <= H * H)) {
                    tsum += sqrtf(fmaxf(q0 + s2, 1e-12f)) +
                            sqrtf(fmaxf(q1 + s2, 1e-12f)) +
                            sqrtf(fmaxf(q2 + s2, 1e-12f)) +
                            sqrtf(fmaxf(q3 + s2, 1e-12f)) +
                            sqrtf(fmaxf(q4 + s2, 1e-12f));
                    tcnt += 1.0f;
                } else {
                    int ti = atomicAdd(tailcnt, 1);
                    tail[ti] = s0 + si;
                }
            }
        }
    }

    // block reduce -> 2 atomics
#pragma unroll
    for (int off = 32; off >= 1; off >>= 1) {
        tsum += __shfl_down(tsum, off);
        tcnt += __shfl_down(tcnt, off);
    }
    const int wv = tid >> 6;
    if ((tid & 63) == 0) { redS[wv] = tsum; redC[wv] = tcnt; }
    __syncthreads();
    if (tid == 0) {
        float s = redS[0] + redS[1] + redS[2] + redS[3];
        float c = redC[0] + redC[1] + redC[2] + redC[3];
        if (s != 0.0f || c != 0.0f) {
            atomicAdd(&acc[0], s);
            atomicAdd(&acc[1], c);
        }
    }
}

// ---- kernel B: brute-force tail sources over all valid targets ----
__global__ __launch_bounds__(BLOCK) void knnB_kernel(
        const float4* __restrict__ pts_s, const float4* __restrict__ pts_t,
        const int* __restrict__ off_t, const int* __restrict__ tail,
        const int* __restrict__ tailcnt, float* __restrict__ acc) {
    __shared__ float bl[4][8];
    const int nv = off_t[NC];
    const int T = *tailcnt;
    const int tid = threadIdx.x;
    const int lane = tid & 63, wv = tid >> 6;
    float bsum = 0.0f, bcnt = 0.0f;

    for (int w = blockIdx.x; w < T; w += gridDim.x) {
        float4 sp = pts_s[tail[w]];
        const float s2 = sp.w;
        const float nx = -2.0f * sp.x, ny = -2.0f * sp.y, nz = -2.0f * sp.z;
        float q0 = 1e20f, q1 = 1e20f, q2 = 1e20f, q3 = 1e20f, q4 = 1e20f;
        for (int i = tid; i < nv; i += BLOCK) {
            float4 t = pts_t[i];
            float q = fmaf(nx, t.x, fmaf(ny, t.y, fmaf(nz, t.z, t.w)));
            INS5(q0, q1, q2, q3, q4, q);
        }
#pragma unroll
        for (int off = 32; off >= 1; off >>= 1) {
            float b0 = __shfl_xor(q0, off);
            float b1 = __shfl_xor(q1, off);
            float b2 = __shfl_xor(q2, off);
            float b3 = __shfl_xor(q3, off);
            float b4 = __shfl_xor(q4, off);
            MERGE55(q0, q1, q2, q3, q4, b0, b1, b2, b3, b4);
        }
        __syncthreads();  // protect bl reuse across loop iterations
        if (lane == 0) {
            bl[wv][0] = q0; bl[wv][1] = q1; bl[wv][2] = q2;
            bl[wv][3] = q3; bl[wv][4] = q4;
        }
        __syncthreads();
        if (tid == 0) {
            float a0 = bl[0][0], a1 = bl[0][1], a2 = bl[0][2], a3 = bl[0][3],
                  a4 = bl[0][4];
#pragma unroll
            for (int k = 1; k < 4; ++k) {
                MERGE55(a0, a1, a2, a3, a4,
                        bl[k][0], bl[k][1], bl[k][2], bl[k][3], bl[k][4]);
            }
            bsum += sqrtf(fmaxf(a0 + s2, 1e-12f)) + sqrtf(fmaxf(a1 + s2, 1e-12f)) +
                    sqrtf(fmaxf(a2 + s2, 1e-12f)) + sqrtf(fmaxf(a3 + s2, 1e-12f)) +
                    sqrtf(fmaxf(a4 + s2, 1e-12f));
            bcnt += 1.0f;
        }
    }
    if (tid == 0 && blockIdx.x < T) {
        atomicAdd(&acc[0], bsum);
        atomicAdd(&acc[1], bcnt);
    }
}

// ================= fallback: round-4 split path =================

__global__ __launch_bounds__(BLOCK, 4) void knn_split_kernel(
        const float* __restrict__ src, const float* __restrict__ tgt,
        float* __restrict__ partials, int ms, int nt, int nth, int spad) {
    __shared__ __align__(16) float xs[TILE_T];
    __shared__ __align__(16) float ys[TILE_T];
    __shared__ __align__(16) float zs[TILE_T];
    __shared__ __align__(16) float w2[TILE_T];

    const int tid = threadIdx.x;
    const int wv = tid >> 6;
    const int lane = tid & 63;
    const int sbase = (blockIdx.x * WAVES_PER_BLOCK + wv) * SRCW;
    const int half = blockIdx.y;
    const int hbase = half * nth;
    const int hend = min(nt, hbase + nth);

    float nx[SRCW], ny[SRCW], nz[SRCW];
#pragma unroll
    for (int s = 0; s < SRCW; ++s) {
        int sp = sbase + s;
        float x = 0.0f, y = 0.0f, z = 0.0f;
        if (sp < ms) {
            x = src[3 * sp + 0];
            y = src[3 * sp + 1];
            z = src[3 * sp + 2];
        }
        nx[s] = -2.0f * x; ny[s] = -2.0f * y; nz[s] = -2.0f * z;
    }
    float q0[SRCW], q1[SRCW], q2[SRCW], q3[SRCW], q4[SRCW];
#pragma unroll
    for (int s = 0; s < SRCW; ++s) {
        q0[s] = 1e30f; q1[s] = 1e30f; q2[s] = 1e30f; q3[s] = 1e30f; q4[s] = 1e30f;
    }

    for (int t0 = hbase; t0 < hend; t0 += TILE_T) {
        int cnt = min(TILE_T, hend - t0);
        for (int t = tid; t < TILE_T; t += BLOCK) {
            float x = 1e10f, y = 0.0f, z = 0.0f;
            if (t < cnt) {
                x = tgt[3 * (size_t)(t0 + t) + 0];
                y = tgt[3 * (size_t)(t0 + t) + 1];
                z = tgt[3 * (size_t)(t0 + t) + 2];
                if (x == 0.0f && y == 0.0f && z == 0.0f) { x = 1e10f; y = 0.0f; z = 0.0f; }
            }
            xs[t] = x; ys[t] = y; zs[t] = z;
            w2[t] = fmaf(x, x, fmaf(y, y, z * z));
        }
        __syncthreads();
#pragma unroll 2
        for (int i = 0; i < TILE_T / 256; ++i) {
            int t = (i << 8) + (lane << 2);
            float4 x4 = *reinterpret_cast<const float4*>(&xs[t]);
            float4 y4 = *reinterpret_cast<const float4*>(&ys[t]);
            float4 z4 = *reinterpret_cast<const float4*>(&zs[t]);
            float4 w4 = *reinterpret_cast<const float4*>(&w2[t]);
#pragma unroll
            for (int s = 0; s < SRCW; ++s) {
                float qa = fmaf(nx[s], x4.x, fmaf(ny[s], y4.x, fmaf(nz[s], z4.x, w4.x)));
                float qb = fmaf(nx[s], x4.y, fmaf(ny[s], y4.y, fmaf(nz[s], z4.y, w4.y)));
                float qc = fmaf(nx[s], x4.z, fmaf(ny[s], y4.z, fmaf(nz[s], z4.z, w4.z)));
                float qd = fmaf(nx[s], x4.w, fmaf(ny[s], y4.w, fmaf(nz[s], z4.w, w4.w)));
                INS5(q0[s], q1[s], q2[s], q3[s], q4[s], qa);
                INS5(q0[s], q1[s], q2[s], q3[s], q4[s], qb);
                INS5(q0[s], q1[s], q2[s], q3[s], q4[s], qc);
                INS5(q0[s], q1[s], q2[s], q3[s], q4[s], qd);
            }
        }
        __syncthreads();
    }
#pragma unroll
    for (int off = 32; off >= 1; off >>= 1) {
#pragma unroll
        for (int s = 0; s < SRCW; ++s) {
            float b0 = __shfl_xor(q0[s], off);
            float b1 = __shfl_xor(q1[s], off);
            float b2 = __shfl_xor(q2[s], off);
            float b3 = __shfl_xor(q3[s], off);
            float b4 = __shfl_xor(q4[s], off);
            MERGE55(q0[s], q1[s], q2[s], q3[s], q4[s], b0, b1, b2, b3, b4);
        }
    }
    if (lane == 0) {
        float* base = partials + ((size_t)half * spad + sbase) * 8;
#pragma unroll
        for (int s = 0; s < SRCW; ++s) {
            if (sbase + s < ms) {
                *reinterpret_cast<float4*>(base + 8 * s) =
                    make_float4(q0[s], q1[s], q2[s], q3[s]);
                *reinterpret_cast<float4*>(base + 8 * s + 4) =
                    make_float4(q4[s], 0.0f, 0.0f, 0.0f);
            }
        }
    }
}

__global__ __launch_bounds__(BLOCK) void merge_kernel(
        const float* __restrict__ src, const float* __restrict__ partials,
        float* __restrict__ acc, int ms, int spad) {
    __shared__ float red_s[WAVES_PER_BLOCK];
    __shared__ float red_c[WAVES_PER_BLOCK];
    const int tid = threadIdx.x;
    const int sp = blockIdx.x * BLOCK + tid;
    float ssum = 0.0f, scnt = 0.0f;
    if (sp < ms) {
        const float* r0p = partials + (size_t)sp * 8;
        const float* r1p = partials + ((size_t)spad + sp) * 8;
        float4 lo0 = *reinterpret_cast<const float4*>(r0p);
        float a4 = r0p[4];
        float4 lo1 = *reinterpret_cast<const float4*>(r1p);
        float b4 = r1p[4];
        float a0 = lo0.x, a1 = lo0.y, a2 = lo0.z, a3 = lo0.w;
        MERGE55(a0, a1, a2, a3, a4, lo1.x, lo1.y, lo1.z, lo1.w, b4);
        float x = src[3 * sp + 0];
        float y = src[3 * sp + 1];
        float z = src[3 * sp + 2];
        bool valid = (x != 0.0f) || (y != 0.0f) || (z != 0.0f);
        float s2 = fmaf(x, x, fmaf(y, y, z * z));
        if (valid) {
            ssum = sqrtf(fmaxf(a0 + s2, 1e-12f)) + sqrtf(fmaxf(a1 + s2, 1e-12f)) +
                   sqrtf(fmaxf(a2 + s2, 1e-12f)) + sqrtf(fmaxf(a3 + s2, 1e-12f)) +
                   sqrtf(fmaxf(a4 + s2, 1e-12f));
            scnt = 1.0f;
        }
    }
#pragma unroll
    for (int off = 32; off >= 1; off >>= 1) {
        ssum += __shfl_down(ssum, off);
        scnt += __shfl_down(scnt, off);
    }
    if ((tid & 63) == 0) { red_s[tid >> 6] = ssum; red_c[tid >> 6] = scnt; }
    __syncthreads();
    if (tid == 0) {
        float s = 0.0f, c = 0.0f;
#pragma unroll
        for (int i = 0; i < WAVES_PER_BLOCK; ++i) { s += red_s[i]; c += red_c[i]; }
        atomicAdd(&acc[0], s);
        atomicAdd(&acc[1], c);
    }
}

// ---------------- launch ----------------

extern "C" void kernel_launch(void* const* d_in, const int* in_sizes, int n_in,
                              void* d_out, int out_size, void* d_ws, size_t ws_size,
                              hipStream_t stream) {
    const float* src = (const float*)d_in[0];
    const float* tgt = (const float*)d_in[1];
    const int ms = in_sizes[0] / 3;
    const int nt = in_sizes[1] / 3;

    // workspace layout (zeroed region first: acc + tailcnt + cnt_t + cnt_s)
    char* p = (char*)d_ws;
    auto take = [&p](size_t bytes) {
        char* r = p;
        p += (bytes + 15) & ~(size_t)15;
        return r;
    };
    float* acc    = (float*)take(16);            // acc[0], acc[1], tailcnt, pad
    int* tailcnt  = (int*)(acc + 2);
    int* cnt_t    = (int*)take(NCPAD * sizeof(int));
    int* cnt_s    = (int*)take(NCPAD * sizeof(int));
    const size_t zero_bytes = (size_t)((char*)(cnt_s + NCPAD) - (char*)d_ws);
    int* off_t    = (int*)take((NCPAD + 1) * sizeof(int));
    int* off_s    = (int*)take((NCPAD + 1) * sizeof(int));
    float4* pts_t = (float4*)take((size_t)nt * sizeof(float4));
    float4* pts_s = (float4*)take((size_t)ms * sizeof(float4));
    int* tail     = (int*)take((size_t)ms * sizeof(int));
    const size_t need_grid = (size_t)(p - (char*)d_ws);

    if (ws_size >= need_grid) {
        const int n = ms + nt;
        hipMemsetAsync(d_ws, 0, zero_bytes, stream);
        bin_count_kernel<<<(n + 255) / 256, 256, 0, stream>>>(src, tgt, ms, nt,
                                                              cnt_s, cnt_t);
        scan_kernel<<<2, 1024, 0, stream>>>(cnt_t, off_t, cnt_s, off_s);
        scatter_kernel<<<(n + 255) / 256, 256, 0, stream>>>(src, tgt, ms, nt,
                                                            cnt_s, cnt_t, pts_s, pts_t);
        knnA_kernel<<<NC, BLOCK, 0, stream>>>(pts_s, pts_t, off_s, off_t,
                                              acc, tail, tailcnt);
        knnB_kernel<<<1024, BLOCK, 0, stream>>>(pts_s, pts_t, off_t, tail,
                                                tailcnt, acc);
        finalize_kernel<<<1, 1, 0, stream>>>(acc, (float*)d_out);
        return;
    }

    // fallback: round-4 split path
    float* acc2 = (float*)d_ws;
    init_acc_kernel<<<1, 1, 0, stream>>>(acc2);
    const int ngroups = (ms + SRC_PER_BLOCK - 1) / SRC_PER_BLOCK;
    const int spad = ngroups * SRC_PER_BLOCK;
    int nth = (nt + NSPLIT - 1) / NSPLIT;
    nth = (nth + TILE_T - 1) / TILE_T * TILE_T;
    float* partials = (float*)((char*)d_ws + 16);
    dim3 grid(ngroups, NSPLIT);
    knn_split_kernel<<<grid, BLOCK, 0, stream>>>(src, tgt, partials, ms, nt, nth, spad);
    merge_kernel<<<(ms + BLOCK - 1) / BLOCK, BLOCK, 0, stream>>>(src, partials,
                                                                 acc2, ms, spad);
    finalize_kernel<<<1, 1, 0, stream>>>(acc2, (float*)d_out);
}

// Round 7
// 96.353 us; speedup vs baseline: 1.5655x; 1.3489x over previous
//
#include <hip/hip_runtime.h>
#include <math.h>

#define KNN 5
#define BLOCK 256

// ---- cell grid ----
#define G 28
#define NC (G * G * G)        // 21952
#define NCPAD 24576           // 24*1024 (padded for the scan kernel)
#define GRANGE 6.0f
#define H (2.0f * GRANGE / (float)G)
#define INVH ((float)G / (2.0f * GRANGE))
#define LPS 16                // lanes per source in query kernel

// ---- fallback (round-4 split path) params ----
#define TILE_T 2048
#define WAVES_PER_BLOCK (BLOCK / 64)
#define SRCW 8
#define SRC_PER_BLOCK (WAVES_PER_BLOCK * SRCW)
#define NSPLIT 2

// ---------------- raw single-instruction min/max ----------------
__device__ __forceinline__ float vmin(float a, float b) {
    float r;
    asm("v_min_f32 %0, %1, %2" : "=v"(r) : "v"(a), "v"(b));
    return r;
}
__device__ __forceinline__ float vmax(float a, float b) {
    float r;
    asm("v_max_f32 %0, %1, %2" : "=v"(r) : "v"(a), "v"(b));
    return r;
}

// sorted top-5 insert: min(Kb,max(Ka,v)) == med3(Ka,Kb,v) for Ka<=Kb
#define INS5(K0, K1, K2, K3, K4, V)                                       \
    do {                                                                  \
        float _v = (V);                                                   \
        K4 = __builtin_amdgcn_fmed3f(K3, K4, _v);                         \
        K3 = __builtin_amdgcn_fmed3f(K2, K3, _v);                         \
        K2 = __builtin_amdgcn_fmed3f(K1, K2, _v);                         \
        K1 = __builtin_amdgcn_fmed3f(K0, K1, _v);                         \
        K0 = vmin(K0, _v);                                                \
    } while (0)

// lowest-5 of two sorted-5 lists (result in a0..a4)
#define MERGE55(a0, a1, a2, a3, a4, b0, b1, b2, b3, b4)                   \
    do {                                                                  \
        float r0 = vmin(a0, b0);                                          \
        float r1 = vmin(vmin(a1, b1), vmax(a0, b0));                      \
        float r2 = vmin(vmin(a2, b2), vmin(vmax(a0, b1), vmax(a1, b0)));  \
        float r3 = vmin(vmin(a3, b3),                                     \
                        vmin(vmax(a0, b2), vmin(vmax(a1, b1), vmax(a2, b0)))); \
        float r4 = vmin(vmin(a4, b4),                                     \
                        vmin(vmin(vmax(a0, b3), vmax(a1, b2)),            \
                             vmin(vmax(a2, b1), vmax(a3, b0))));          \
        a0 = r0; a1 = r1; a2 = r2; a3 = r3; a4 = r4;                      \
    } while (0)

// ---------------- tiny kernels ----------------
__global__ void finalize_kernel(const float* acc, float* out) {
    out[0] = acc[0] / (acc[1] * (float)KNN);
}
__global__ void init_acc_kernel(float* acc) { acc[0] = 0.0f; acc[1] = 0.0f; }

// ================= grid pipeline =================

__device__ __forceinline__ int cell_of(float x, float y, float z) {
    int cx = (int)floorf((x + GRANGE) * INVH);
    int cy = (int)floorf((y + GRANGE) * INVH);
    int cz = (int)floorf((z + GRANGE) * INVH);
    cx = min(max(cx, 0), G - 1);
    cy = min(max(cy, 0), G - 1);
    cz = min(max(cz, 0), G - 1);
    return (cz * G + cy) * G + cx;
}

__global__ void bin_count_kernel(const float* __restrict__ src,
                                 const float* __restrict__ tgt,
                                 int ms, int nt,
                                 int* __restrict__ cnt_s,
                                 int* __restrict__ cnt_t) {
    int i = blockIdx.x * blockDim.x + threadIdx.x;
    int n = ms + nt;
    for (; i < n; i += gridDim.x * blockDim.x) {
        bool isT = (i >= ms);
        const float* p = isT ? (tgt + 3 * (size_t)(i - ms)) : (src + 3 * (size_t)i);
        float x = p[0], y = p[1], z = p[2];
        if (isT && x == 0.0f && y == 0.0f && z == 0.0f) continue;
        atomicAdd((isT ? cnt_t : cnt_s) + cell_of(x, y, z), 1);
    }
}

// exclusive scan of NCPAD padded counts (pads are zero from the memset).
// gridDim.x == 2: block 0 -> targets, block 1 -> sources.
__global__ __launch_bounds__(1024) void scan_kernel(int* ct, int* ot, int* cs, int* os) {
    __shared__ int psum[1024];
    int* c = blockIdx.x ? cs : ct;
    int* o = blockIdx.x ? os : ot;
    const int t = threadIdx.x;
    int4 v[6];
    const int4* c4 = reinterpret_cast<const int4*>(c) + t * 6;
#pragma unroll
    for (int j = 0; j < 6; ++j) v[j] = c4[j];
    int s = 0;
#pragma unroll
    for (int j = 0; j < 6; ++j) s += v[j].x + v[j].y + v[j].z + v[j].w;
    psum[t] = s;
    __syncthreads();
    for (int d = 1; d < 1024; d <<= 1) {
        int x = (t >= d) ? psum[t - d] : 0;
        __syncthreads();
        psum[t] += x;
        __syncthreads();
    }
    int run = t ? psum[t - 1] : 0;
    int4* o4 = reinterpret_cast<int4*>(o) + t * 6;
    int4* cc4 = reinterpret_cast<int4*>(c) + t * 6;
#pragma unroll
    for (int j = 0; j < 6; ++j) {
        int4 w;
        w.x = run; run += v[j].x;
        w.y = run; run += v[j].y;
        w.z = run; run += v[j].z;
        w.w = run; run += v[j].w;
        o4[j] = w;
        cc4[j] = w;  // cursor for scatter
    }
    if (t == 1023) o[NCPAD] = run;
}

__global__ void scatter_kernel(const float* __restrict__ src,
                               const float* __restrict__ tgt,
                               int ms, int nt,
                               int* __restrict__ cur_s, int* __restrict__ cur_t,
                               float4* __restrict__ pts_s,
                               float4* __restrict__ pts_t) {
    int i = blockIdx.x * blockDim.x + threadIdx.x;
    int n = ms + nt;
    for (; i < n; i += gridDim.x * blockDim.x) {
        bool isT = (i >= ms);
        const float* p = isT ? (tgt + 3 * (size_t)(i - ms)) : (src + 3 * (size_t)i);
        float x = p[0], y = p[1], z = p[2];
        if (isT && x == 0.0f && y == 0.0f && z == 0.0f) continue;
        int cell = cell_of(x, y, z);
        int slot = atomicAdd((isT ? cur_t : cur_s) + cell, 1);
        float w = fmaf(x, x, fmaf(y, y, z * z));
        (isT ? pts_t : pts_s)[slot] = make_float4(x, y, z, w);
    }
}

// ---- flat query: 16 lanes per cell-sorted source, slab-pruned ring-1 ----
__global__ __launch_bounds__(BLOCK) void knn_query_kernel(
        const float4* __restrict__ pts_s, const float4* __restrict__ pts_t,
        const int* __restrict__ off_t, float* __restrict__ acc,
        int* __restrict__ tail, int* __restrict__ tailcnt, int ms) {
    __shared__ float redS[4], redC[4];

    const int tid = threadIdx.x;
    const int g = tid >> 4;     // group (source) within block: 16 per block
    const int m = tid & 15;     // lane within group
    const int sidx = blockIdx.x * (BLOCK / LPS) + g;
    const bool live = (sidx < ms);

    float4 sp = pts_s[live ? sidx : 0];
    const float s2 = sp.w;
    const float nx = -2.0f * sp.x, ny = -2.0f * sp.y, nz = -2.0f * sp.z;

    int cx = (int)floorf((sp.x + GRANGE) * INVH);
    int cy = (int)floorf((sp.y + GRANGE) * INVH);
    int cz = (int)floorf((sp.z + GRANGE) * INVH);
    cx = min(max(cx, 0), G - 1);
    cy = min(max(cy, 0), G - 1);
    cz = min(max(cz, 0), G - 1);
    const int xlo = max(cx - 1, 0), xhi = min(cx + 1, G - 1);
    const float y0 = -GRANGE + cy * H, y1 = y0 + H;
    const float z0 = -GRANGE + cz * H, z1 = z0 + H;

    float q0 = 1e20f, q1 = 1e20f, q2 = 1e20f, q3 = 1e20f, q4 = 1e20f;

    // ---- own row (3 cells), unpruned ----
    {
        const int base = (cz * G + cy) * G;
        const int st = off_t[base + xlo];
        const int en = off_t[base + xhi + 1];
        for (int i = st + m; i < en; i += LPS) {
            float4 t = pts_t[i];
            float q = fmaf(nx, t.x, fmaf(ny, t.y, fmaf(nz, t.z, t.w)));
            INS5(q0, q1, q2, q3, q4, q);
        }
    }

    // ---- merged d5^2 bound (non-destructive butterfly) ----
    float lim;
    {
        float m0 = q0, m1 = q1, m2 = q2, m3 = q3, m4 = q4;
#pragma unroll
        for (int o = 8; o >= 1; o >>= 1) {
            float b0 = __shfl_xor(m0, o);
            float b1 = __shfl_xor(m1, o);
            float b2 = __shfl_xor(m2, o);
            float b3 = __shfl_xor(m3, o);
            float b4 = __shfl_xor(m4, o);
            MERGE55(m0, m1, m2, m3, m4, b0, b1, b2, b3, b4);
        }
        lim = m4 + s2;  // current exact d5^2 (group-uniform)
    }

    // ---- 8 remaining rows, slab-pruned ----
    const int DYA[8] = {-1, 1, 0, 0, -1, -1, 1, 1};
    const int DZA[8] = {0, 0, -1, 1, -1, 1, -1, 1};
#pragma unroll
    for (int r = 0; r < 8; ++r) {
        const int yy = cy + DYA[r], zz = cz + DZA[r];
        if ((unsigned)yy >= G || (unsigned)zz >= G) continue;
        float dys = (DYA[r] < 0) ? (sp.y - y0) : ((DYA[r] > 0) ? (y1 - sp.y) : 0.0f);
        float dzs = (DZA[r] < 0) ? (sp.z - z0) : ((DZA[r] > 0) ? (z1 - sp.z) : 0.0f);
        dys = fmaxf(dys, 0.0f);  // clamped sources can sit outside their cell
        dzs = fmaxf(dzs, 0.0f);
        const float rb = fmaf(dys, dys, dzs * dzs);
        if (lim > rb) {
            const int base = (zz * G + yy) * G;
            const int st = off_t[base + xlo];
            const int en = off_t[base + xhi + 1];
            for (int i = st + m; i < en; i += LPS) {
                float4 t = pts_t[i];
                float q = fmaf(nx, t.x, fmaf(ny, t.y, fmaf(nz, t.z, t.w)));
                INS5(q0, q1, q2, q3, q4, q);
            }
        }
    }

    // ---- final merge (destructive, all lanes get result) ----
#pragma unroll
    for (int o = 8; o >= 1; o >>= 1) {
        float b0 = __shfl_xor(q0, o);
        float b1 = __shfl_xor(q1, o);
        float b2 = __shfl_xor(q2, o);
        float b3 = __shfl_xor(q3, o);
        float b4 = __shfl_xor(q4, o);
        MERGE55(q0, q1, q2, q3, q4, b0, b1, b2, b3, b4);
    }

    float tsum = 0.0f, tcnt = 0.0f;
    if (live && m == 0) {
        const bool valid = (sp.x != 0.0f) || (sp.y != 0.0f) || (sp.z != 0.0f);
        if (valid) {
            const bool inbox = fabsf(sp.x) <= GRANGE && fabsf(sp.y) <= GRANGE &&
                               fabsf(sp.z) <= GRANGE;
            if (inbox && (q4 + s2 <= H * H)) {  // exact: rest of space >= H away
                tsum = sqrtf(fmaxf(q0 + s2, 1e-12f)) + sqrtf(fmaxf(q1 + s2, 1e-12f)) +
                       sqrtf(fmaxf(q2 + s2, 1e-12f)) + sqrtf(fmaxf(q3 + s2, 1e-12f)) +
                       sqrtf(fmaxf(q4 + s2, 1e-12f));
                tcnt = 1.0f;
            } else {
                int ti = atomicAdd(tailcnt, 1);
                tail[ti] = sidx;
            }
        }
    }

    // block reduce -> 2 atomics
#pragma unroll
    for (int off = 32; off >= 1; off >>= 1) {
        tsum += __shfl_down(tsum, off);
        tcnt += __shfl_down(tcnt, off);
    }
    const int wv = tid >> 6;
    if ((tid & 63) == 0) { redS[wv] = tsum; redC[wv] = tcnt; }
    __syncthreads();
    if (tid == 0) {
        float s = redS[0] + redS[1] + redS[2] + redS[3];
        float c = redC[0] + redC[1] + redC[2] + redC[3];
        if (s != 0.0f || c != 0.0f) {
            atomicAdd(&acc[0], s);
            atomicAdd(&acc[1], c);
        }
    }
}

// ---- kernel B: brute-force tail sources over all valid targets ----
__global__ __launch_bounds__(BLOCK) void knnB_kernel(
        const float4* __restrict__ pts_s, const float4* __restrict__ pts_t,
        const int* __restrict__ off_t, const int* __restrict__ tail,
        const int* __restrict__ tailcnt, float* __restrict__ acc) {
    __shared__ float bl[4][8];
    const int nv = off_t[NC];
    const int T = *tailcnt;
    const int tid = threadIdx.x;
    const int lane = tid & 63, wv = tid >> 6;
    float bsum = 0.0f, bcnt = 0.0f;

    for (int w = blockIdx.x; w < T; w += gridDim.x) {
        float4 sp = pts_s[tail[w]];
        const float s2 = sp.w;
        const float nx = -2.0f * sp.x, ny = -2.0f * sp.y, nz = -2.0f * sp.z;
        float q0 = 1e20f, q1 = 1e20f, q2 = 1e20f, q3 = 1e20f, q4 = 1e20f;
        for (int i = tid; i < nv; i += BLOCK) {
            float4 t = pts_t[i];
            float q = fmaf(nx, t.x, fmaf(ny, t.y, fmaf(nz, t.z, t.w)));
            INS5(q0, q1, q2, q3, q4, q);
        }
#pragma unroll
        for (int off = 32; off >= 1; off >>= 1) {
            float b0 = __shfl_xor(q0, off);
            float b1 = __shfl_xor(q1, off);
            float b2 = __shfl_xor(q2, off);
            float b3 = __shfl_xor(q3, off);
            float b4 = __shfl_xor(q4, off);
            MERGE55(q0, q1, q2, q3, q4, b0, b1, b2, b3, b4);
        }
        __syncthreads();
        if (lane == 0) {
            bl[wv][0] = q0; bl[wv][1] = q1; bl[wv][2] = q2;
            bl[wv][3] = q3; bl[wv][4] = q4;
        }
        __syncthreads();
        if (tid == 0) {
            float a0 = bl[0][0], a1 = bl[0][1], a2 = bl[0][2], a3 = bl[0][3],
                  a4 = bl[0][4];
#pragma unroll
            for (int k = 1; k < 4; ++k) {
                MERGE55(a0, a1, a2, a3, a4,
                        bl[k][0], bl[k][1], bl[k][2], bl[k][3], bl[k][4]);
            }
            bsum += sqrtf(fmaxf(a0 + s2, 1e-12f)) + sqrtf(fmaxf(a1 + s2, 1e-12f)) +
                    sqrtf(fmaxf(a2 + s2, 1e-12f)) + sqrtf(fmaxf(a3 + s2, 1e-12f)) +
                    sqrtf(fmaxf(a4 + s2, 1e-12f));
            bcnt += 1.0f;
        }
    }
    if (tid == 0 && blockIdx.x < T) {
        atomicAdd(&acc[0], bsum);
        atomicAdd(&acc[1], bcnt);
    }
}

// ================= fallback: round-4 split path =================

__global__ __launch_bounds__(BLOCK, 4) void knn_split_kernel(
        const float* __restrict__ src, const float* __restrict__ tgt,
        float* __restrict__ partials, int ms, int nt, int nth, int spad) {
    __shared__ __align__(16) float xs[TILE_T];
    __shared__ __align__(16) float ys[TILE_T];
    __shared__ __align__(16) float zs[TILE_T];
    __shared__ __align__(16) float w2[TILE_T];

    const int tid = threadIdx.x;
    const int wv = tid >> 6;
    const int lane = tid & 63;
    const int sbase = (blockIdx.x * WAVES_PER_BLOCK + wv) * SRCW;
    const int half = blockIdx.y;
    const int hbase = half * nth;
    const int hend = min(nt, hbase + nth);

    float nx[SRCW], ny[SRCW], nz[SRCW];
#pragma unroll
    for (int s = 0; s < SRCW; ++s) {
        int sp = sbase + s;
        float x = 0.0f, y = 0.0f, z = 0.0f;
        if (sp < ms) {
            x = src[3 * sp + 0];
            y = src[3 * sp + 1];
            z = src[3 * sp + 2];
        }
        nx[s] = -2.0f * x; ny[s] = -2.0f * y; nz[s] = -2.0f * z;
    }
    float q0[SRCW], q1[SRCW], q2[SRCW], q3[SRCW], q4[SRCW];
#pragma unroll
    for (int s = 0; s < SRCW; ++s) {
        q0[s] = 1e30f; q1[s] = 1e30f; q2[s] = 1e30f; q3[s] = 1e30f; q4[s] = 1e30f;
    }

    for (int t0 = hbase; t0 < hend; t0 += TILE_T) {
        int cnt = min(TILE_T, hend - t0);
        for (int t = tid; t < TILE_T; t += BLOCK) {
            float x = 1e10f, y = 0.0f, z = 0.0f;
            if (t < cnt) {
                x = tgt[3 * (size_t)(t0 + t) + 0];
                y = tgt[3 * (size_t)(t0 + t) + 1];
                z = tgt[3 * (size_t)(t0 + t) + 2];
                if (x == 0.0f && y == 0.0f && z == 0.0f) { x = 1e10f; y = 0.0f; z = 0.0f; }
            }
            xs[t] = x; ys[t] = y; zs[t] = z;
            w2[t] = fmaf(x, x, fmaf(y, y, z * z));
        }
        __syncthreads();
#pragma unroll 2
        for (int i = 0; i < TILE_T / 256; ++i) {
            int t = (i << 8) + (lane << 2);
            float4 x4 = *reinterpret_cast<const float4*>(&xs[t]);
            float4 y4 = *reinterpret_cast<const float4*>(&ys[t]);
            float4 z4 = *reinterpret_cast<const float4*>(&zs[t]);
            float4 w4 = *reinterpret_cast<const float4*>(&w2[t]);
#pragma unroll
            for (int s = 0; s < SRCW; ++s) {
                float qa = fmaf(nx[s], x4.x, fmaf(ny[s], y4.x, fmaf(nz[s], z4.x, w4.x)));
                float qb = fmaf(nx[s], x4.y, fmaf(ny[s], y4.y, fmaf(nz[s], z4.y, w4.y)));
                float qc = fmaf(nx[s], x4.z, fmaf(ny[s], y4.z, fmaf(nz[s], z4.z, w4.z)));
                float qd = fmaf(nx[s], x4.w, fmaf(ny[s], y4.w, fmaf(nz[s], z4.w, w4.w)));
                INS5(q0[s], q1[s], q2[s], q3[s], q4[s], qa);
                INS5(q0[s], q1[s], q2[s], q3[s], q4[s], qb);
                INS5(q0[s], q1[s], q2[s], q3[s], q4[s], qc);
                INS5(q0[s], q1[s], q2[s], q3[s], q4[s], qd);
            }
        }
        __syncthreads();
    }
#pragma unroll
    for (int off = 32; off >= 1; off >>= 1) {
#pragma unroll
        for (int s = 0; s < SRCW; ++s) {
            float b0 = __shfl_xor(q0[s], off);
            float b1 = __shfl_xor(q1[s], off);
            float b2 = __shfl_xor(q2[s], off);
            float b3 = __shfl_xor(q3[s], off);
            float b4 = __shfl_xor(q4[s], off);
            MERGE55(q0[s], q1[s], q2[s], q3[s], q4[s], b0, b1, b2, b3, b4);
        }
    }
    if (lane == 0) {
        float* base = partials + ((size_t)half * spad + sbase) * 8;
#pragma unroll
        for (int s = 0; s < SRCW; ++s) {
            if (sbase + s < ms) {
                *reinterpret_cast<float4*>(base + 8 * s) =
                    make_float4(q0[s], q1[s], q2[s], q3[s]);
                *reinterpret_cast<float4*>(base + 8 * s + 4) =
                    make_float4(q4[s], 0.0f, 0.0f, 0.0f);
            }
        }
    }
}

__global__ __launch_bounds__(BLOCK) void merge_kernel(
        const float* __restrict__ src, const float* __restrict__ partials,
        float* __restrict__ acc, int ms, int spad) {
    __shared__ float red_s[WAVES_PER_BLOCK];
    __shared__ float red_c[WAVES_PER_BLOCK];
    const int tid = threadIdx.x;
    const int sp = blockIdx.x * BLOCK + tid;
    float ssum = 0.0f, scnt = 0.0f;
    if (sp < ms) {
        const float* r0p = partials + (size_t)sp * 8;
        const float* r1p = partials + ((size_t)spad + sp) * 8;
        float4 lo0 = *reinterpret_cast<const float4*>(r0p);
        float a4 = r0p[4];
        float4 lo1 = *reinterpret_cast<const float4*>(r1p);
        float b4 = r1p[4];
        float a0 = lo0.x, a1 = lo0.y, a2 = lo0.z, a3 = lo0.w;
        MERGE55(a0, a1, a2, a3, a4, lo1.x, lo1.y, lo1.z, lo1.w, b4);
        float x = src[3 * sp + 0];
        float y = src[3 * sp + 1];
        float z = src[3 * sp + 2];
        bool valid = (x != 0.0f) || (y != 0.0f) || (z != 0.0f);
        float s2 = fmaf(x, x, fmaf(y, y, z * z));
        if (valid) {
            ssum = sqrtf(fmaxf(a0 + s2, 1e-12f)) + sqrtf(fmaxf(a1 + s2, 1e-12f)) +
                   sqrtf(fmaxf(a2 + s2, 1e-12f)) + sqrtf(fmaxf(a3 + s2, 1e-12f)) +
                   sqrtf(fmaxf(a4 + s2, 1e-12f));
            scnt = 1.0f;
        }
    }
#pragma unroll
    for (int off = 32; off >= 1; off >>= 1) {
        ssum += __shfl_down(ssum, off);
        scnt += __shfl_down(scnt, off);
    }
    if ((tid & 63) == 0) { red_s[tid >> 6] = ssum; red_c[tid >> 6] = scnt; }
    __syncthreads();
    if (tid == 0) {
        float s = 0.0f, c = 0.0f;
#pragma unroll
        for (int i = 0; i < WAVES_PER_BLOCK; ++i) { s += red_s[i]; c += red_c[i]; }
        atomicAdd(&acc[0], s);
        atomicAdd(&acc[1], c);
    }
}

// ---------------- launch ----------------

extern "C" void kernel_launch(void* const* d_in, const int* in_sizes, int n_in,
                              void* d_out, int out_size, void* d_ws, size_t ws_size,
                              hipStream_t stream) {
    const float* src = (const float*)d_in[0];
    const float* tgt = (const float*)d_in[1];
    const int ms = in_sizes[0] / 3;
    const int nt = in_sizes[1] / 3;

    // workspace layout (zeroed region first: acc + tailcnt + cnt_t + cnt_s)
    char* p = (char*)d_ws;
    auto take = [&p](size_t bytes) {
        char* r = p;
        p += (bytes + 15) & ~(size_t)15;
        return r;
    };
    float* acc    = (float*)take(16);            // acc[0], acc[1], tailcnt, pad
    int* tailcnt  = (int*)(acc + 2);
    int* cnt_t    = (int*)take(NCPAD * sizeof(int));
    int* cnt_s    = (int*)take(NCPAD * sizeof(int));
    const size_t zero_bytes = (size_t)((char*)(cnt_s + NCPAD) - (char*)d_ws);
    int* off_t    = (int*)take((NCPAD + 1) * sizeof(int));
    int* off_s    = (int*)take((NCPAD + 1) * sizeof(int));
    float4* pts_t = (float4*)take((size_t)nt * sizeof(float4));
    float4* pts_s = (float4*)take((size_t)ms * sizeof(float4));
    int* tail     = (int*)take((size_t)ms * sizeof(int));
    const size_t need_grid = (size_t)(p - (char*)d_ws);

    if (ws_size >= need_grid) {
        const int n = ms + nt;
        hipMemsetAsync(d_ws, 0, zero_bytes, stream);
        bin_count_kernel<<<(n + 255) / 256, 256, 0, stream>>>(src, tgt, ms, nt,
                                                              cnt_s, cnt_t);
        scan_kernel<<<2, 1024, 0, stream>>>(cnt_t, off_t, cnt_s, off_s);
        scatter_kernel<<<(n + 255) / 256, 256, 0, stream>>>(src, tgt, ms, nt,
                                                            cnt_s, cnt_t, pts_s, pts_t);
        const int qblocks = (ms + (BLOCK / LPS) - 1) / (BLOCK / LPS);
        knn_query_kernel<<<qblocks, BLOCK, 0, stream>>>(pts_s, pts_t, off_t, acc,
                                                        tail, tailcnt, ms);
        knnB_kernel<<<1024, BLOCK, 0, stream>>>(pts_s, pts_t, off_t, tail,
                                                tailcnt, acc);
        finalize_kernel<<<1, 1, 0, stream>>>(acc, (float*)d_out);
        return;
    }

    // fallback: round-4 split path
    float* acc2 = (float*)d_ws;
    init_acc_kernel<<<1, 1, 0, stream>>>(acc2);
    const int ngroups = (ms + SRC_PER_BLOCK - 1) / SRC_PER_BLOCK;
    const int spad = ngroups * SRC_PER_BLOCK;
    int nth = (nt + NSPLIT - 1) / NSPLIT;
    nth = (nth + TILE_T - 1) / TILE_T * TILE_T;
    float* partials = (float*)((char*)d_ws + 16);
    dim3 grid(ngroups, NSPLIT);
    knn_split_kernel<<<grid, BLOCK, 0, stream>>>(src, tgt, partials, ms, nt, nth, spad);
    merge_kernel<<<(ms + BLOCK - 1) / BLOCK, BLOCK, 0, stream>>>(src, partials,
                                                                 acc2, ms, spad);
    finalize_kernel<<<1, 1, 0, stream>>>(acc2, (float*)d_out);
}